// Round 6
// baseline (1023.928 us; speedup 1.0000x reference)
//
#include <hip/hip_runtime.h>

// EMD approx-match (Fan et al. approxmatch.cu), B=8, N=M=4096.
// R=2 rows/thread -> 4 blocks/CU (16 waves/CU) to fill issue stalls;
// software-pipelined LDS->reg groups; 4-op fma-chain exp arguments.
// Structure: A(0); per level: B sweep + fused C(l)/A(l+1) sweep; level 9
// (coef 0) in closed form.

#define BB 8
#define NN 4096
#define MM 4096

constexpr int BLK   = 256;  // threads per block (4 waves)
constexpr int S     = 16;   // inner-loop split lanes per row-group
constexpr int R     = 2;    // rows per thread
constexpr int RPB   = (BLK / S) * R;   // 32 rows per block
constexpr int CHUNK = 1024; // LDS staging chunk
constexpr int G     = (CHUNK / S) / 4; // 16 groups of 4 j-iters

#if defined(__has_builtin)
#if __has_builtin(__builtin_amdgcn_exp2f)
#define EXP2F(x) __builtin_amdgcn_exp2f(x)
#endif
#if __has_builtin(__builtin_amdgcn_logf)
#define LOG2F(x) __builtin_amdgcn_logf(x)
#endif
#endif
#ifndef EXP2F
#define EXP2F(x) exp2f(x)
#endif
#ifndef LOG2F
#define LOG2F(x) log2f(x)
#endif

__global__ void emd_init(float* __restrict__ satl, float* __restrict__ satr,
                         float* __restrict__ bsum, float* __restrict__ slsum,
                         float* __restrict__ scal, float* __restrict__ out) {
    int i = blockIdx.x * blockDim.x + threadIdx.x;
    if (i < BB * NN) satl[i] = 1.0f;
    if (i < BB * MM) satr[i] = 1.0f;
    if (i < BB)      bsum[i] = 0.0f;
    if (i < BB)      slsum[i] = 0.0f;
    if (i < BB * 5)  scal[i] = 0.0f;
    if (i == 0)      out[0]  = 0.0f;
}

// ---------- Pass A (level 0 only): sl[n] = satl[n]/(rowsum + 1e-9) ----------
// staged w = c*qq + log2(satr[m]); arg = (w + cpp[r]) via 4-op fma chain
#define AB_LOAD(vv, gg)                                          \
    _Pragma("unroll")                                            \
    for (int k = 0; k < 4; ++k) vv[k] = q[((gg)*4 + k)*S + s];

#define AB_COMP(vv)                                              \
    _Pragma("unroll")                                            \
    for (int k = 0; k < 4; ++k) {                                \
        float4 v = vv[k];                                        \
        _Pragma("unroll")                                        \
        for (int r = 0; r < R; ++r) {                            \
            float a0 = v.w + cpp[r];                             \
            float a1 = fmaf(zs[r], v.z, a0);                     \
            float a2 = fmaf(ys[r], v.y, a1);                     \
            float arg = fmaf(xs[r], v.x, a2);                    \
            acc[r] += EXP2F(arg);                                \
        }                                                        \
    }

__global__ __launch_bounds__(BLK, 4) void emd_passA(
        const float* __restrict__ xyz1, const float* __restrict__ xyz2,
        const float* __restrict__ satl, const float* __restrict__ satr,
        float* __restrict__ sl, float c) {
    __shared__ float4 q[CHUNK];                  // 16 KB
    const int b    = blockIdx.x / (NN / RPB);
    const int tile = blockIdx.x % (NN / RPB);
    const float* x2b = xyz2 + (size_t)b * MM * 3;
    const float* srb = satr + (size_t)b * MM;

    const int g = threadIdx.x / S, s = threadIdx.x % S;
    const int n0 = tile * RPB + g * R;
    const float* p = xyz1 + ((size_t)b * NN + n0) * 3;
    const float m2c = -2.0f * c;
    float xs[R], ys[R], zs[R], cpp[R], acc[R];
    #pragma unroll
    for (int r = 0; r < R; ++r) {
        float x = p[3*r], y = p[3*r+1], z = p[3*r+2];
        cpp[r] = c * (x*x + y*y + z*z);
        xs[r] = m2c * x; ys[r] = m2c * y; zs[r] = m2c * z;
        acc[r] = 0.0f;
    }

    for (int c0 = 0; c0 < MM; c0 += CHUNK) {
        __syncthreads();
        for (int m = threadIdx.x; m < CHUNK; m += BLK) {
            int mm = c0 + m;
            float xx = x2b[3*mm], yy = x2b[3*mm+1], zz = x2b[3*mm+2];
            float qq = xx*xx + yy*yy + zz*zz;
            q[m] = make_float4(xx, yy, zz, fmaf(c, qq, LOG2F(srb[mm])));
        }
        __syncthreads();
        float4 va[4], vb[4];
        AB_LOAD(va, 0);
        #pragma unroll 1
        for (int gs = 0; gs < G; gs += 2) {
            AB_LOAD(vb, gs + 1);
            AB_COMP(va);
            if (gs + 2 < G) { AB_LOAD(va, gs + 2); }
            AB_COMP(vb);
        }
    }
    #pragma unroll
    for (int r = 0; r < R; ++r) {
        acc[r] += __shfl_xor(acc[r], 1);
        acc[r] += __shfl_xor(acc[r], 2);
        acc[r] += __shfl_xor(acc[r], 4);
        acc[r] += __shfl_xor(acc[r], 8);
    }
    if (s == 0) {
        #pragma unroll
        for (int r = 0; r < R; ++r) {
            int gi = b * NN + n0 + r;
            sl[gi] = satl[gi] / (acc[r] + 1e-9f);
        }
    }
}

// ---------- Pass B: colsum + fused ratio + satr update ----------
__global__ __launch_bounds__(BLK, 4) void emd_passB(
        const float* __restrict__ xyz1, const float* __restrict__ xyz2,
        const float* __restrict__ sl, float* __restrict__ satr,
        float* __restrict__ sr2, float* __restrict__ bsum,
        int do_sum, float c) {
    __shared__ float4 q[CHUNK];                  // 16 KB (rows n staged)
    const int b    = blockIdx.x / (MM / RPB);
    const int tile = blockIdx.x % (MM / RPB);
    const float* x1b = xyz1 + (size_t)b * NN * 3;
    const float* slb = sl + (size_t)b * NN;

    const int g = threadIdx.x / S, s = threadIdx.x % S;
    const int m0 = tile * RPB + g * R;
    const float* qp = xyz2 + ((size_t)b * MM + m0) * 3;
    const float m2c = -2.0f * c;
    float xs[R], ys[R], zs[R], cpp[R], acc[R];
    #pragma unroll
    for (int r = 0; r < R; ++r) {
        float x = qp[3*r], y = qp[3*r+1], z = qp[3*r+2];
        cpp[r] = c * (x*x + y*y + z*z);
        xs[r] = m2c * x; ys[r] = m2c * y; zs[r] = m2c * z;
        acc[r] = 0.0f;
    }

    for (int c0 = 0; c0 < NN; c0 += CHUNK) {
        __syncthreads();
        for (int n = threadIdx.x; n < CHUNK; n += BLK) {
            int nn = c0 + n;
            float xx = x1b[3*nn], yy = x1b[3*nn+1], zz = x1b[3*nn+2];
            float pp = xx*xx + yy*yy + zz*zz;
            q[n] = make_float4(xx, yy, zz, fmaf(c, pp, LOG2F(slb[nn])));
        }
        __syncthreads();
        float4 va[4], vb[4];
        AB_LOAD(va, 0);
        #pragma unroll 1
        for (int gs = 0; gs < G; gs += 2) {
            AB_LOAD(vb, gs + 1);
            AB_COMP(va);
            if (gs + 2 < G) { AB_LOAD(va, gs + 2); }
            AB_COMP(vb);
        }
    }
    #pragma unroll
    for (int r = 0; r < R; ++r) {
        acc[r] += __shfl_xor(acc[r], 1);
        acc[r] += __shfl_xor(acc[r], 2);
        acc[r] += __shfl_xor(acc[r], 4);
        acc[r] += __shfl_xor(acc[r], 8);
    }
    float part = 0.0f;
    if (s == 0) {
        #pragma unroll
        for (int r = 0; r < R; ++r) {
            int gi = b * MM + m0 + r;
            float sr    = satr[gi];
            float ss2   = acc[r] * sr;
            float ratio = fminf(sr / (ss2 + 1e-9f), 1.0f);
            float sn    = fmaxf(sr - ss2 * ratio, 0.0f);
            sr2[gi]  = sr * ratio;
            satr[gi] = sn;
            part += sn;
        }
    }
    if (do_sum) {
        part += __shfl_xor(part, 1);
        part += __shfl_xor(part, 2);
        part += __shfl_xor(part, 4);
        part += __shfl_xor(part, 8);
        part += __shfl_xor(part, 16);
        part += __shfl_xor(part, 32);
        if ((threadIdx.x & 63) == 0) atomicAdd(&bsum[b], part);
    }
}

// ---------- Fused C(l)+A(l+1), l=0..7 (cl = 4*cn): 1 exp/element ----------
#define CA0_LOAD(vv, ww, gg)                                     \
    _Pragma("unroll")                                            \
    for (int k = 0; k < 4; ++k) {                                \
        int idx = ((gg)*4 + k)*S + s;                            \
        vv[k] = q[idx]; ww[k] = w[idx];                          \
    }

#define CA0_COMP(vv, ww)                                         \
    _Pragma("unroll")                                            \
    for (int k = 0; k < 4; ++k) {                                \
        float4 v = vv[k]; float2 wv = ww[k];                     \
        _Pragma("unroll")                                        \
        for (int r = 0; r < R; ++r) {                            \
            float a0 = v.w + cnpp[r];                            \
            float a1 = fmaf(zs[r], v.z, a0);                     \
            float a2 = fmaf(ys[r], v.y, a1);                     \
            float arg = fmaf(xs[r], v.x, a2);                    \
            float en  = EXP2F(arg);                              \
            acc2[r] = fmaf(en, wv.y, acc2[r]);                   \
            float e2 = en * en;                                  \
            float t  = (e2 * e2) * wv.x;                         \
            rd[r]   += t;                                        \
            costA[r] = fmaf(t, arg, costA[r]);                   \
        }                                                        \
    }

__global__ __launch_bounds__(BLK, 4) void emd_passCA0(
        const float* __restrict__ xyz1, const float* __restrict__ xyz2,
        float* __restrict__ sl, float* __restrict__ satl,
        const float* __restrict__ sr2, const float* __restrict__ satr_next,
        float* __restrict__ out, float cl, float cn) {
    __shared__ float4 q[CHUNK];    // (x2,y2,z2, cn*qq) 16 KB
    __shared__ float2 w[CHUNK];    // (sr2[m], satr_next[m]) 8 KB
    const int b    = blockIdx.x / (NN / RPB);
    const int tile = blockIdx.x % (NN / RPB);
    const float* x2b = xyz2 + (size_t)b * MM * 3;
    const float* s2b = sr2 + (size_t)b * MM;
    const float* srb = satr_next + (size_t)b * MM;

    const int g = threadIdx.x / S, s = threadIdx.x % S;
    const int n0 = tile * RPB + g * R;
    const float* pp_ = xyz1 + ((size_t)b * NN + n0) * 3;
    const float m2cn = -2.0f * cn;
    const float icn  = 1.0f / cn;
    float xs[R], ys[R], zs[R], cnpp[R], rd[R], costA[R], acc2[R], slv[R];
    #pragma unroll
    for (int r = 0; r < R; ++r) {
        float x = pp_[3*r], y = pp_[3*r+1], z = pp_[3*r+2];
        cnpp[r] = cn * (x*x + y*y + z*z);
        xs[r] = m2cn * x; ys[r] = m2cn * y; zs[r] = m2cn * z;
        rd[r] = 0.0f; costA[r] = 0.0f; acc2[r] = 0.0f;
        slv[r] = sl[b * NN + n0 + r];
    }

    for (int c0 = 0; c0 < MM; c0 += CHUNK) {
        __syncthreads();
        for (int m = threadIdx.x; m < CHUNK; m += BLK) {
            int mm = c0 + m;
            float xx = x2b[3*mm], yy = x2b[3*mm+1], zz = x2b[3*mm+2];
            float qq = xx*xx + yy*yy + zz*zz;
            q[m] = make_float4(xx, yy, zz, cn * qq);
            w[m] = make_float2(s2b[mm], srb[mm]);
        }
        __syncthreads();

        float4 va[4], vb[4]; float2 wa[4], wb[4];
        CA0_LOAD(va, wa, 0);
        #pragma unroll 1
        for (int gs = 0; gs < G; gs += 2) {
            CA0_LOAD(vb, wb, gs + 1);
            CA0_COMP(va, wa);
            if (gs + 2 < G) { CA0_LOAD(va, wa, gs + 2); }
            CA0_COMP(vb, wb);
        }
    }

    #pragma unroll
    for (int r = 0; r < R; ++r) {
        rd[r] += __shfl_xor(rd[r], 1);
        rd[r] += __shfl_xor(rd[r], 2);
        rd[r] += __shfl_xor(rd[r], 4);
        rd[r] += __shfl_xor(rd[r], 8);
        acc2[r] += __shfl_xor(acc2[r], 1);
        acc2[r] += __shfl_xor(acc2[r], 2);
        acc2[r] += __shfl_xor(acc2[r], 4);
        acc2[r] += __shfl_xor(acc2[r], 8);
    }

    float csum = 0.0f;
    #pragma unroll
    for (int r = 0; r < R; ++r) csum += (costA[r] * icn) * slv[r];
    csum += __shfl_xor(csum, 1);
    csum += __shfl_xor(csum, 2);
    csum += __shfl_xor(csum, 4);
    csum += __shfl_xor(csum, 8);
    csum += __shfl_xor(csum, 16);
    csum += __shfl_xor(csum, 32);
    if ((threadIdx.x & 63) == 0)
        atomicAdd(out, csum * (1.0f / (float)(BB * NN)));

    if (s == 0) {
        #pragma unroll
        for (int r = 0; r < R; ++r) {
            int gi = b * NN + n0 + r;
            float sa = fmaxf(satl[gi] - rd[r] * slv[r], 0.0f);
            satl[gi] = sa;
            sl[gi] = sa / (acc2[r] + 1e-9f);
        }
    }
}

// ---------- Fused C(8)+A(9): cn==0 path; also accumulates slsum ----------
// staged v.w = cl*qq + lw, qa = lw where lw = log2(max(sr2,1e-30)).
// sum t*d2 = (sum t*arg - sum t*lw)/cl
#define CA1_LOAD(vv, aa, gg)                                     \
    _Pragma("unroll")                                            \
    for (int k = 0; k < 4; ++k) {                                \
        int idx = ((gg)*4 + k)*S + s;                            \
        vv[k] = q[idx]; aa[k] = qa[idx];                         \
    }

#define CA1_COMP(vv, aa)                                         \
    _Pragma("unroll")                                            \
    for (int k = 0; k < 4; ++k) {                                \
        float4 v = vv[k]; float lw = aa[k];                      \
        _Pragma("unroll")                                        \
        for (int r = 0; r < R; ++r) {                            \
            float a0 = v.w + clpp[r];                            \
            float a1 = fmaf(zs[r], v.z, a0);                     \
            float a2 = fmaf(ys[r], v.y, a1);                     \
            float arg = fmaf(xs[r], v.x, a2);                    \
            float t   = EXP2F(arg);                              \
            rd[r] += t;                                          \
            c1[r] = fmaf(t, arg, c1[r]);                         \
            c2[r] = fmaf(t, lw, c2[r]);                          \
        }                                                        \
    }

__global__ __launch_bounds__(BLK, 4) void emd_passCA1(
        const float* __restrict__ xyz1, const float* __restrict__ xyz2,
        float* __restrict__ sl, float* __restrict__ satl,
        const float* __restrict__ sr2, const float* __restrict__ bsum,
        float* __restrict__ slsum, float* __restrict__ out, float cl) {
    __shared__ float4 q[CHUNK];    // (x2,y2,z2, cl*qq + lw) 16 KB
    __shared__ float  qa[CHUNK];   // lw                      4 KB
    const int b    = blockIdx.x / (NN / RPB);
    const int tile = blockIdx.x % (NN / RPB);
    const float* x2b = xyz2 + (size_t)b * MM * 3;
    const float* s2b = sr2 + (size_t)b * MM;

    const int g = threadIdx.x / S, s = threadIdx.x % S;
    const int n0 = tile * RPB + g * R;
    const float* pp_ = xyz1 + ((size_t)b * NN + n0) * 3;
    const float m2cl = -2.0f * cl;
    const float icl  = 1.0f / cl;
    float xs[R], ys[R], zs[R], clpp[R], rd[R], c1[R], c2[R], slv[R];
    #pragma unroll
    for (int r = 0; r < R; ++r) {
        float x = pp_[3*r], y = pp_[3*r+1], z = pp_[3*r+2];
        clpp[r] = cl * (x*x + y*y + z*z);
        xs[r] = m2cl * x; ys[r] = m2cl * y; zs[r] = m2cl * z;
        rd[r] = 0.0f; c1[r] = 0.0f; c2[r] = 0.0f;
        slv[r] = sl[b * NN + n0 + r];
    }

    for (int c0 = 0; c0 < MM; c0 += CHUNK) {
        __syncthreads();
        for (int m = threadIdx.x; m < CHUNK; m += BLK) {
            int mm = c0 + m;
            float xx = x2b[3*mm], yy = x2b[3*mm+1], zz = x2b[3*mm+2];
            float qq = xx*xx + yy*yy + zz*zz;
            float lw = LOG2F(fmaxf(s2b[mm], 1e-30f));
            q[m]  = make_float4(xx, yy, zz, fmaf(cl, qq, lw));
            qa[m] = lw;
        }
        __syncthreads();

        float4 va[4], vb[4]; float aa[4], ab[4];
        CA1_LOAD(va, aa, 0);
        #pragma unroll 1
        for (int gs = 0; gs < G; gs += 2) {
            CA1_LOAD(vb, ab, gs + 1);
            CA1_COMP(va, aa);
            if (gs + 2 < G) { CA1_LOAD(va, aa, gs + 2); }
            CA1_COMP(vb, ab);
        }
    }

    #pragma unroll
    for (int r = 0; r < R; ++r) {
        rd[r] += __shfl_xor(rd[r], 1);
        rd[r] += __shfl_xor(rd[r], 2);
        rd[r] += __shfl_xor(rd[r], 4);
        rd[r] += __shfl_xor(rd[r], 8);
    }

    float csum = 0.0f;
    #pragma unroll
    for (int r = 0; r < R; ++r) csum += ((c1[r] - c2[r]) * icl) * slv[r];
    csum += __shfl_xor(csum, 1);
    csum += __shfl_xor(csum, 2);
    csum += __shfl_xor(csum, 4);
    csum += __shfl_xor(csum, 8);
    csum += __shfl_xor(csum, 16);
    csum += __shfl_xor(csum, 32);
    if ((threadIdx.x & 63) == 0)
        atomicAdd(out, csum * (1.0f / (float)(BB * NN)));

    float part = 0.0f;
    if (s == 0) {
        float bs = bsum[b];
        #pragma unroll
        for (int r = 0; r < R; ++r) {
            int gi = b * NN + n0 + r;
            float sa = fmaxf(satl[gi] - rd[r] * slv[r], 0.0f);
            satl[gi] = sa;
            float s9 = sa / (bs + 1e-9f);
            sl[gi] = s9;
            part += s9;
        }
    }
    part += __shfl_xor(part, 1);
    part += __shfl_xor(part, 2);
    part += __shfl_xor(part, 4);
    part += __shfl_xor(part, 8);
    part += __shfl_xor(part, 16);
    part += __shfl_xor(part, 32);
    if ((threadIdx.x & 63) == 0) atomicAdd(&slsum[b], part);
}

// ---------- Level 9 (coef 0) closed form ----------
__global__ void emd_lvl9_col(const float* __restrict__ xyz2,
                             const float* __restrict__ satr,
                             const float* __restrict__ slsum,
                             float* __restrict__ scal) {
    int i = blockIdx.x * blockDim.x + threadIdx.x;   // over B*M
    int b = i / MM;
    const float* qp = xyz2 + (size_t)i * 3;
    float sr = satr[i];
    float ss2 = sr * slsum[b];
    float ratio = fminf(sr / (ss2 + 1e-9f), 1.0f);
    float s2 = sr * ratio;
    float x = qp[0], y = qp[1], z = qp[2];
    float v0 = s2, v1 = s2*x, v2 = s2*y, v3 = s2*z;
    float v4 = s2 * (x*x + y*y + z*z);
    #pragma unroll
    for (int d = 1; d < 64; d <<= 1) {
        v0 += __shfl_xor(v0, d); v1 += __shfl_xor(v1, d);
        v2 += __shfl_xor(v2, d); v3 += __shfl_xor(v3, d);
        v4 += __shfl_xor(v4, d);
    }
    if ((threadIdx.x & 63) == 0) {
        atomicAdd(&scal[b*5+0], v0); atomicAdd(&scal[b*5+1], v1);
        atomicAdd(&scal[b*5+2], v2); atomicAdd(&scal[b*5+3], v3);
        atomicAdd(&scal[b*5+4], v4);
    }
}

__global__ void emd_lvl9_cost(const float* __restrict__ xyz1,
                              const float* __restrict__ sl,
                              const float* __restrict__ scal,
                              float* __restrict__ out) {
    int i = blockIdx.x * blockDim.x + threadIdx.x;   // over B*N
    int b = i / NN;
    float W  = scal[b*5+0], Wx = scal[b*5+1], Wy = scal[b*5+2];
    float Wz = scal[b*5+3], Q  = scal[b*5+4];
    const float* p = xyz1 + (size_t)i * 3;
    float x = p[0], y = p[1], z = p[2];
    float pp = x*x + y*y + z*z;
    float dotw = x*Wx + y*Wy + z*Wz;
    float c = sl[i] * (pp * W + Q - 2.0f * dotw);
    #pragma unroll
    for (int d = 1; d < 64; d <<= 1) c += __shfl_xor(c, d);
    if ((threadIdx.x & 63) == 0)
        atomicAdd(out, c * (1.0f / (float)(BB * NN)));
}

extern "C" void kernel_launch(void* const* d_in, const int* in_sizes, int n_in,
                              void* d_out, int out_size, void* d_ws, size_t ws_size,
                              hipStream_t stream) {
    const float* xyz1 = (const float*)d_in[0];   // [B,N,3]
    const float* xyz2 = (const float*)d_in[1];   // [B,M,3]
    float* out  = (float*)d_out;                 // scalar

    float* satl  = (float*)d_ws;                 // B*N
    float* sl    = satl  + BB * NN;              // B*N
    float* satr  = sl    + BB * NN;              // B*M
    float* sr2   = satr  + BB * MM;              // B*M
    float* bsum  = sr2   + BB * MM;              // B
    float* slsum = bsum  + BB;                   // B
    float* scal  = slsum + BB;                   // B*5

    emd_init<<<(BB * NN + 255) / 256, 256, 0, stream>>>(satl, satr, bsum,
                                                        slsum, scal, out);

    const double levels[10] = {-16384.0, -4096.0, -1024.0, -256.0, -64.0,
                               -16.0, -4.0, -1.0, -0.25, 0.0};
    const double LOG2E = 1.4426950408889634;
    float c[10];
    for (int l = 0; l < 10; ++l) c[l] = (float)(levels[l] * LOG2E);

    const int grid = BB * (NN / RPB);   // 1024 blocks = 4 per CU

    emd_passA<<<grid, BLK, 0, stream>>>(xyz1, xyz2, satl, satr, sl, c[0]);
    for (int l = 0; l <= 8; ++l) {
        emd_passB<<<grid, BLK, 0, stream>>>(xyz1, xyz2, sl, satr, sr2, bsum,
                                            (l == 8) ? 1 : 0, c[l]);
        if (l < 8)
            emd_passCA0<<<grid, BLK, 0, stream>>>(
                xyz1, xyz2, sl, satl, sr2, satr, out, c[l], c[l + 1]);
        else
            emd_passCA1<<<grid, BLK, 0, stream>>>(
                xyz1, xyz2, sl, satl, sr2, bsum, slsum, out, c[l]);
    }
    emd_lvl9_col<<<BB * MM / 256, 256, 0, stream>>>(xyz2, satr, slsum, scal);
    emd_lvl9_cost<<<BB * NN / 256, 256, 0, stream>>>(xyz1, sl, scal, out);
}